// Round 2
// baseline (986.223 us; speedup 1.0000x reference)
//
#include <hip/hip_runtime.h>

#define CAP 32
#define K 16

// ---------------------------------------------------------------------------
// Kernel 1: runtime sparsification of W1 (general; for this input nnz=1/row).
// ---------------------------------------------------------------------------
__global__ void sparsify_kernel(const float* __restrict__ W1, int N,
                                int* __restrict__ cnts, int* __restrict__ cols,
                                float* __restrict__ wts) {
  __shared__ int scnt;
  const int row = blockIdx.x;
  if (threadIdx.x == 0) scnt = 0;
  __syncthreads();
  const float* wr = W1 + (long)row * N;
  for (int k = threadIdx.x; k < N; k += blockDim.x) {
    float w = wr[k];
    if (w != 0.0f) {
      int slot = atomicAdd(&scnt, 1);
      if (slot < CAP) {
        cols[row * CAP + slot] = k;
        wts[row * CAP + slot] = w;
      }
    }
  }
  __syncthreads();
  if (threadIdx.x == 0) {
    cnts[row] = scnt;
    if (scnt == 0) { cols[row * CAP] = 0; wts[row * CAP] = 0.0f; }
  }
}

// ---------------------------------------------------------------------------
// Kernel 2: warm input_batch into LLC so the recurrence's prefetch loads
// retire from cache (~300-500 cyc) instead of HBM (~900 cyc).
// ---------------------------------------------------------------------------
__global__ void touch_kernel(const float4* __restrict__ x4, long n4,
                             float* __restrict__ dump) {
  long i = (long)blockIdx.x * blockDim.x + threadIdx.x;
  const long stride = (long)gridDim.x * blockDim.x;
  float acc = 0.f;
  for (; i < n4; i += stride) {
    float4 v = x4[i];
    acc += v.x + v.y + v.z + v.w;
  }
  if (acc == 1234.56789f) dump[blockIdx.x & 1023] = acc;  // defeat DCE
}

// ---------------------------------------------------------------------------
// One Izhikevich step, bitwise numpy op order (contract off at kernel scope).
// Updates v,u in place; writes spike value to sout.
// ---------------------------------------------------------------------------
#define IZH_STEP(xv, sout)                        \
  {                                               \
    const float I = w0 * (xv);                    \
    float t1 = 0.04f * v;                         \
    float t2 = t1 * v;                            \
    float t3 = 5.0f * v;                          \
    float t4 = t2 + t3;                           \
    float t5 = t4 + 140.0f;                       \
    float t6 = t5 - u;                            \
    float t7 = t6 + I;                            \
    float vn = v + t7;      /* dt==1: exact */    \
    float q1 = bn * v;                            \
    float q2 = q1 - u;                            \
    float q3 = Pn * q2;                           \
    float un = u + q3;                            \
    float df = vn - thn;                          \
    bool sp = df > 0.0f;                          \
    v = sp ? cn : vn;       /* == vn*(1-s)+c*s */ \
    u = un + (sp ? dn : 0.0f); /* == un + d*s */  \
    sout = sp ? 1.0f : 0.0f;                      \
  }

// ---------------------------------------------------------------------------
// Kernel 3: single-wave self-contained recurrence, vmcnt-budgeted.
//   16 blocks x 64 threads; each wave owns 64 neurons end-to-end.
//   K=16 steps/batch:
//     per batch = 16 loads (prefetch next batch) + 48 stores (s,v,u)
//     => max ~64 outstanding vmem ops, and the compiler's automatic wait
//        before the first prefetched element is vmcnt(63) -- encodable, and
//        already satisfied by in-order retirement (load issued ~800 cyc
//        earlier vs ~300-500 cyc LLC latency). Stores stay fire-and-forget;
//        no vmcnt clamp, no drain, no barrier, no LDS.
//   (K=32 variant measured 179 cyc/step: 128 outstanding ops blew the 63-cap
//    and forced clamped over-draining waits -- in-order store retirement
//    leaked onto the critical path.)
// ---------------------------------------------------------------------------
__global__ void __launch_bounds__(64) izh_wave_kernel(
    const float* __restrict__ X, const float* __restrict__ state,
    const float* __restrict__ a, const float* __restrict__ b,
    const float* __restrict__ c, const float* __restrict__ d,
    const float* __restrict__ th, const float* __restrict__ dtv,
    const float* __restrict__ W1,
    const int* __restrict__ cnts, const int* __restrict__ cols,
    const float* __restrict__ wts,
    float* __restrict__ o_s, float* __restrict__ o_st,
    int T, int N)
{
#pragma clang fp contract(off)
  const int lane = threadIdx.x & 63;
  const int base = blockIdx.x * 64;
  const int gn   = base + lane;
  const int N2   = 2 * N;

  // wave-uniform path decision
  bool elig = (base + 64 <= N);
  if (elig) elig = (cnts[gn] == 1) && (dtv[gn] == 1.0f);
  const bool fast = (__ballot(elig) == ~0ULL);

  if (fast) {
    float v = state[gn], u = state[N + gn];
    const float an  = a[gn], bn = b[gn], cn = c[gn], dn = d[gn];
    const float thn = th[gn];
    const float Pn  = dtv[gn] * an;        // same operands/order as ref's dt*a
    const float w0  = wts[gn * CAP];
    const int   c0  = cols[gn * CAP];
    const int   B   = T / K;
    const float* Xp = X + c0;              // per-lane column base

    float xA[K], xB[K];
    if (B >= 1) {
#pragma unroll
      for (int i = 0; i < K; ++i) xA[i] = Xp[(size_t)i * N];
    }

    // one batch of K steps from register buffer XR, batch index kk
    // (32-bit scalar offsets: max index T*N*2 = 16.8M < 2^31)
#define DO_BATCH(XR, kk)                                   \
    {                                                      \
      int tS = (kk) * K * N;                               \
      int tV = (kk) * K * N2;                              \
      _Pragma("unroll")                                    \
      for (int i = 0; i < K; ++i) {                        \
        float s_;                                          \
        IZH_STEP(XR[i], s_);                               \
        o_s[tS + gn] = s_;                                 \
        o_st[tV + gn] = v;                                 \
        o_st[tV + N + gn] = u;                             \
        tS += N; tV += N2;                                 \
      }                                                    \
    }

    int k = 0;
    for (; k + 1 < B; k += 2) {
      // prefetch batch k+1 (issued before batch k's 48 stores)
#pragma unroll
      for (int i = 0; i < K; ++i)
        xB[i] = Xp[(size_t)((k + 1) * K + i) * N];
      DO_BATCH(xA, k);
      // prefetch batch k+2 while computing batch k+1
      if (k + 2 < B) {
#pragma unroll
        for (int i = 0; i < K; ++i)
          xA[i] = Xp[(size_t)((k + 2) * K + i) * N];
      }
      DO_BATCH(xB, k + 1);
    }
    if (k < B) DO_BATCH(xA, k);            // odd-B leftover batch

    // tail (T % K != 0): direct loads (rare)
    for (int t = B * K; t < T; ++t) {
      float s_;
      IZH_STEP(Xp[(size_t)t * N], s_);
      o_s[(long)t * N + gn] = s_;
      o_st[(long)t * N2 + gn] = v;
      o_st[(long)t * N2 + N + gn] = u;
    }
#undef DO_BATCH
  } else {
    // ---- general fallback: any cnt / dt ----
    if (gn >= N) return;
    float v = state[gn], u = state[N + gn];
    const float an = a[gn], bn = b[gn], cn = c[gn], dn = d[gn];
    const float thn = th[gn], dtn = dtv[gn];
    const float Pn = dtn * an;
    const int cnt = cnts[gn];
    for (int t = 0; t < T; ++t) {
      float I = 0.0f;
      if (cnt <= CAP) {
        for (int j = 0; j < cnt; ++j)
          I = I + wts[gn * CAP + j] * X[(size_t)t * N + cols[gn * CAP + j]];
      } else {
        const float* wr = W1 + (size_t)gn * N;
        const float* xr = X + (size_t)t * N;
        for (int kk = 0; kk < N; ++kk) I = I + wr[kk] * xr[kk];
      }
      float t1 = 0.04f * v; float t2 = t1 * v; float t3 = 5.0f * v;
      float t4 = t2 + t3; float t5 = t4 + 140.0f; float t6 = t5 - u;
      float t7 = t6 + I; float t8 = dtn * t7; float vn = v + t8;
      float q1 = bn * v; float q2 = q1 - u; float q3 = Pn * q2; float un = u + q3;
      float df = vn - thn; bool sp = df > 0.0f;
      v = sp ? cn : vn; u = un + (sp ? dn : 0.0f);
      o_s[(size_t)t * N + gn] = sp ? 1.0f : 0.0f;
      o_st[(size_t)t * (2L * N) + gn] = v;
      o_st[(size_t)t * (2L * N) + N + gn] = u;
    }
  }
}

// ---------------------------------------------------------------------------
// Kernel 4: r[t] = W2 @ s[t]  (exact: terms are 20*{0,1}, sums < 2^24)
// ---------------------------------------------------------------------------
__global__ void decode_dot_kernel(const float* __restrict__ o_s,
                                  const float* __restrict__ W2,
                                  float* __restrict__ r, int N) {
  const int t = blockIdx.x;
  const float* srow = o_s + (long)t * N;
  float p = 0.0f;
  for (int n = threadIdx.x; n < N; n += blockDim.x)
    p += W2[n] * srow[n];
  for (int off = 32; off > 0; off >>= 1) p += __shfl_down(p, off);
  __shared__ float red[4];
  if ((threadIdx.x & 63) == 0) red[threadIdx.x >> 6] = p;
  __syncthreads();
  if (threadIdx.x == 0) {
    float tot = 0.f;
    const int nw = blockDim.x >> 6;
    for (int w = 0; w < nw; ++w) tot += red[w];
    r[t] = tot;
  }
}

// ---------------------------------------------------------------------------
// Kernel 5: dm[t] = leak*dm[t-1] + r[t], chunked affine scan (1 block, 64 thr)
// Tolerance on decoded output is large; reassociation across chunks is fine.
// ---------------------------------------------------------------------------
__global__ void decode_scan_kernel(const float* __restrict__ r,
                                   const float* __restrict__ leakp,
                                   float* __restrict__ out, int T) {
  __shared__ float Bsh[64], Ssh[64];
  const float leakv = leakp[0];
  const int i = threadIdx.x;                 // 0..63
  const int chunk = (T + 63) / 64;
  const int t0 = i * chunk;
  float B = 0.0f;
  for (int j = 0; j < chunk; ++j) {
    int t = t0 + j;
    if (t < T) B = leakv * B + r[t];
  }
  Bsh[i] = B;
  float A = 1.0f, p = leakv; int e = chunk;
  while (e) { if (e & 1) A *= p; p *= p; e >>= 1; }
  __syncthreads();
  if (i == 0) {
    float dm = 0.0f;
    for (int k = 0; k < 64; ++k) { Ssh[k] = dm; dm = A * dm + Bsh[k]; }
  }
  __syncthreads();
  float dm = Ssh[i];
  for (int j = 0; j < chunk; ++j) {
    int t = t0 + j;
    if (t < T) { dm = leakv * dm + r[t]; out[t] = dm; }
  }
}

// ---------------------------------------------------------------------------
extern "C" void kernel_launch(void* const* d_in, const int* in_sizes, int n_in,
                              void* d_out, int out_size, void* d_ws, size_t ws_size,
                              hipStream_t stream) {
  const float* X  = (const float*)d_in[0];
  const float* st = (const float*)d_in[1];
  const float* W1 = (const float*)d_in[2];
  const float* W2 = (const float*)d_in[3];
  const float* a  = (const float*)d_in[4];
  const float* b  = (const float*)d_in[5];
  const float* c  = (const float*)d_in[6];
  const float* d  = (const float*)d_in[7];
  const float* th = (const float*)d_in[8];
  const float* dt = (const float*)d_in[9];
  const float* lk = (const float*)d_in[10];
  const int N = in_sizes[4];          // a has N elements
  const int T = in_sizes[0] / N;

  float* o_s  = (float*)d_out;               // outputs  [T,N]
  float* o_st = o_s + (long)T * N;           // states   [T,2,N]
  float* o_dm = o_st + 2L * (long)T * N;     // decoded  [T,1]

  int*   cnts = (int*)d_ws;                  // N
  int*   cols = cnts + N;                    // N*CAP
  float* wts  = (float*)(cols + (long)N * CAP); // N*CAP
  float* rbuf = wts + (long)N * CAP;         // T
  float* dump = rbuf + T;                    // toucher sink

  sparsify_kernel<<<N, 256, 0, stream>>>(W1, N, cnts, cols, wts);
  const long n4 = ((long)T * N) / 4;
  touch_kernel<<<1024, 256, 0, stream>>>((const float4*)X, n4, dump);
  const int nblk = (N + 63) / 64;
  izh_wave_kernel<<<nblk, 64, 0, stream>>>(X, st, a, b, c, d, th, dt, W1,
                                           cnts, cols, wts, o_s, o_st, T, N);
  decode_dot_kernel<<<T, 256, 0, stream>>>(o_s, W2, rbuf, N);
  decode_scan_kernel<<<1, 64, 0, stream>>>(rbuf, lk, o_dm, T);
}

// Round 3
// 616.289 us; speedup vs baseline: 1.6003x; 1.6003x over previous
//
#include <hip/hip_runtime.h>

#define CAP 32
#define K 32   // steps per batch (obuf = 2*K*3*64*4 = 48 KiB LDS)

// ---------------------------------------------------------------------------
// Kernel 1: runtime sparsification of W1 (general; for this input nnz=1/row).
// ---------------------------------------------------------------------------
__global__ void sparsify_kernel(const float* __restrict__ W1, int N,
                                int* __restrict__ cnts, int* __restrict__ cols,
                                float* __restrict__ wts) {
  __shared__ int scnt;
  const int row = blockIdx.x;
  if (threadIdx.x == 0) scnt = 0;
  __syncthreads();
  const float* wr = W1 + (long)row * N;
  for (int k = threadIdx.x; k < N; k += blockDim.x) {
    float w = wr[k];
    if (w != 0.0f) {
      int slot = atomicAdd(&scnt, 1);
      if (slot < CAP) {
        cols[row * CAP + slot] = k;
        wts[row * CAP + slot] = w;
      }
    }
  }
  __syncthreads();
  if (threadIdx.x == 0) {
    cnts[row] = scnt;
    if (scnt == 0) { cols[row * CAP] = 0; wts[row * CAP] = 0.0f; }
  }
}

// ---------------------------------------------------------------------------
// Kernel 2: warm input_batch into LLC so the compute wave's batch-ahead
// prefetch loads retire well before consumption.
// ---------------------------------------------------------------------------
__global__ void touch_kernel(const float4* __restrict__ x4, long n4,
                             float* __restrict__ dump) {
  long i = (long)blockIdx.x * blockDim.x + threadIdx.x;
  const long stride = (long)gridDim.x * blockDim.x;
  float acc = 0.f;
  for (; i < n4; i += stride) {
    float4 v = x4[i];
    acc += v.x + v.y + v.z + v.w;
  }
  if (acc == 1234.56789f) dump[blockIdx.x & 1023] = acc;  // defeat DCE
}

// ---------------------------------------------------------------------------
// One Izhikevich step, bitwise numpy op order (contract off at kernel scope).
// ---------------------------------------------------------------------------
#define IZH_STEP(xv, sout)                        \
  {                                               \
    const float I = w0 * (xv);                    \
    float t1 = 0.04f * v;                         \
    float t2 = t1 * v;                            \
    float t3 = 5.0f * v;                          \
    float t4 = t2 + t3;                           \
    float t5 = t4 + 140.0f;                       \
    float t6 = t5 - u;                            \
    float t7 = t6 + I;                            \
    float vn = v + t7;      /* dt==1: exact */    \
    float q1 = bn * v;                            \
    float q2 = q1 - u;                            \
    float q3 = Pn * q2;                           \
    float un = u + q3;                            \
    float df = vn - thn;                          \
    bool sp = df > 0.0f;                          \
    v = sp ? cn : vn;       /* == vn*(1-s)+c*s */ \
    u = un + (sp ? dn : 0.0f); /* == un + d*s */  \
    sout = sp ? 1.0f : 0.0f;                      \
  }

// ---------------------------------------------------------------------------
// Kernel 3: producer/consumer with RAW barriers (no vmcnt drain, ever).
//   Block = 256 thr (4 waves) per 64 neurons; grid = N/64.
//     wave0: compute. Loads x DIRECTLY global->reg (its vmem queue holds
//            ONLY loads -> the wait before consuming a batch-ahead prefetch
//            is trivially satisfied; no store ever sits ahead of it in the
//            in-order retirement queue). Writes s,v,u to LDS. ZERO stores.
//     wave1/2/3: s/v/u writers. LDS-read -> fire-and-forget dwordx4 stores.
//   Sync = __builtin_amdgcn_s_barrier() + explicit lgkmcnt(0) on wave0 only.
//   Unlike __syncthreads(), this emits NO s_waitcnt vmcnt(0): writer stores
//   stay in flight across barriers (HK T3/T4 discipline). The R0 kernel's
//   1100 cyc/batch barrier-drain tax and the R1/R2 kernels' per-batch
//   store-queue drain on the compute wave are both gone.
// ---------------------------------------------------------------------------
__global__ void __launch_bounds__(256) izh_pc_kernel(
    const float* __restrict__ X, const float* __restrict__ state,
    const float* __restrict__ a, const float* __restrict__ b,
    const float* __restrict__ c, const float* __restrict__ d,
    const float* __restrict__ th, const float* __restrict__ dtv,
    const float* __restrict__ W1,
    const int* __restrict__ cnts, const int* __restrict__ cols,
    const float* __restrict__ wts,
    float* __restrict__ o_s, float* __restrict__ o_st,
    int T, int N)
{
#pragma clang fp contract(off)
  __shared__ float obuf[2][K][3][64];     // [buf][step][s,v,u][lane]
  __shared__ int s_fast;

  const int wid  = threadIdx.x >> 6;
  const int lane = threadIdx.x & 63;
  const int base = blockIdx.x * 64;
  const int gn   = base + lane;
  const long N2  = 2L * N;
  const int B    = T / K;

  // ---- block-uniform path decision ----
  if (wid == 0) {
    bool elig = (base + 64 <= N);
    if (elig) elig = (cnts[gn] == 1) && (dtv[gn] == 1.0f);
    unsigned long long m = __ballot(elig);
    if (lane == 0) s_fast = (m == ~0ULL) ? 1 : 0;
  }
  __syncthreads();

  if (s_fast) {
    if (wid == 0) {
      // ================= compute wave =================
      float v = state[gn], u = state[N + gn];
      const float bn = b[gn], cn = c[gn], dn = d[gn], thn = th[gn];
      const float Pn = dtv[gn] * a[gn];    // same operands/order as ref's dt*a
      const float w0 = wts[gn * CAP];
      const int   c0 = cols[gn * CAP];
      const float* Xp = X + c0;

      float xA[K], xB[K];
      if (B >= 1) {
#pragma unroll
        for (int i = 0; i < K; ++i) xA[i] = Xp[(size_t)i * N];
      }

      // one batch: K steps from reg buffer XR into obuf[bsel], then barrier.
      // lgkmcnt(0) flushes the ds_writes; NO vmcnt wait is emitted.
#define COMPUTE(XR, bsel)                                      \
      {                                                        \
        _Pragma("unroll")                                      \
        for (int i = 0; i < K; ++i) {                          \
          float s_;                                            \
          IZH_STEP(XR[i], s_);                                 \
          obuf[bsel][i][0][lane] = s_;                         \
          obuf[bsel][i][1][lane] = v;                          \
          obuf[bsel][i][2][lane] = u;                          \
        }                                                      \
        asm volatile("s_waitcnt lgkmcnt(0)" ::: "memory");     \
        __builtin_amdgcn_s_barrier();                          \
      }

      int k = 0;
      for (; k + 1 < B; k += 2) {
        // prefetch batch k+1 while computing batch k
#pragma unroll
        for (int i = 0; i < K; ++i)
          xB[i] = Xp[(size_t)((k + 1) * K + i) * N];
        COMPUTE(xA, 0)
        // prefetch batch k+2 while computing batch k+1
        if (k + 2 < B) {
#pragma unroll
          for (int i = 0; i < K; ++i)
            xA[i] = Xp[(size_t)((k + 2) * K + i) * N];
        }
        COMPUTE(xB, 1)
      }
      if (k < B) COMPUTE(xA, 0)            // odd-B leftover (bsel = k&1 = 0)
#undef COMPUTE

      // tail (T % K != 0): direct global stores (none for T=8192,K=32)
      for (int t = B * K; t < T; ++t) {
        float s_;
        IZH_STEP(Xp[(size_t)t * N], s_);
        o_s[(long)t * N + gn] = s_;
        o_st[(long)t * N2 + gn] = v;
        o_st[(long)t * N2 + N + gn] = u;
      }
    } else {
      // ================= writer waves =================
      const int cidx = wid - 1;            // 0:s 1:v 2:u
      float* P; long RS;
      if (wid == 1)      { P = o_s;      RS = N;  }
      else if (wid == 2) { P = o_st;     RS = N2; }
      else               { P = o_st + N; RS = N2; }
      const int r = lane >> 4, j = lane & 15;

      for (int k = 0; k < B; ++k) {
        if (k > 0) {
          const int q = k - 1, bsel = q & 1, t0 = q * K;
#pragma unroll
          for (int i = 0; i < K; i += 4) {
            float4 val = *(const float4*)&obuf[bsel][i + r][cidx][4 * j];
            *(float4*)(P + (size_t)(t0 + i + r) * RS + base + 4 * j) = val;
          }
        }
        __builtin_amdgcn_s_barrier();      // raw: stores stay in flight
      }
      if (B > 0) {                         // drain last staged batch
        const int q = B - 1, bsel = q & 1, t0 = q * K;
#pragma unroll
        for (int i = 0; i < K; i += 4) {
          float4 val = *(const float4*)&obuf[bsel][i + r][cidx][4 * j];
          *(float4*)(P + (size_t)(t0 + i + r) * RS + base + 4 * j) = val;
        }
      }
    }
  } else {
    // ---- general fallback: wave0 threads only, any cnt / dt ----
    if (wid != 0 || gn >= N) return;
    float v = state[gn], u = state[N + gn];
    const float an = a[gn], bn = b[gn], cn = c[gn], dn = d[gn];
    const float thn = th[gn], dtn = dtv[gn];
    const float Pn = dtn * an;
    const int cnt = cnts[gn];
    for (int t = 0; t < T; ++t) {
      float I = 0.0f;
      if (cnt <= CAP) {
        for (int j = 0; j < cnt; ++j)
          I = I + wts[gn * CAP + j] * X[(size_t)t * N + cols[gn * CAP + j]];
      } else {
        const float* wr = W1 + (size_t)gn * N;
        const float* xr = X + (size_t)t * N;
        for (int kk = 0; kk < N; ++kk) I = I + wr[kk] * xr[kk];
      }
      float t1 = 0.04f * v; float t2 = t1 * v; float t3 = 5.0f * v;
      float t4 = t2 + t3; float t5 = t4 + 140.0f; float t6 = t5 - u;
      float t7 = t6 + I; float t8 = dtn * t7; float vn = v + t8;
      float q1 = bn * v; float q2 = q1 - u; float q3 = Pn * q2; float un = u + q3;
      float df = vn - thn; bool sp = df > 0.0f;
      v = sp ? cn : vn; u = un + (sp ? dn : 0.0f);
      o_s[(size_t)t * N + gn] = sp ? 1.0f : 0.0f;
      o_st[(size_t)t * N2 + gn] = v;
      o_st[(size_t)t * N2 + N + gn] = u;
    }
  }
}

// ---------------------------------------------------------------------------
// Kernel 4: r[t] = W2 @ s[t]  (exact: terms are 20*{0,1}, sums < 2^24)
// ---------------------------------------------------------------------------
__global__ void decode_dot_kernel(const float* __restrict__ o_s,
                                  const float* __restrict__ W2,
                                  float* __restrict__ r, int N) {
  const int t = blockIdx.x;
  const float* srow = o_s + (long)t * N;
  float p = 0.0f;
  for (int n = threadIdx.x; n < N; n += blockDim.x)
    p += W2[n] * srow[n];
  for (int off = 32; off > 0; off >>= 1) p += __shfl_down(p, off);
  __shared__ float red[4];
  if ((threadIdx.x & 63) == 0) red[threadIdx.x >> 6] = p;
  __syncthreads();
  if (threadIdx.x == 0) {
    float tot = 0.f;
    const int nw = blockDim.x >> 6;
    for (int w = 0; w < nw; ++w) tot += red[w];
    r[t] = tot;
  }
}

// ---------------------------------------------------------------------------
// Kernel 5: dm[t] = leak*dm[t-1] + r[t], chunked affine scan (1 block, 64 thr)
// ---------------------------------------------------------------------------
__global__ void decode_scan_kernel(const float* __restrict__ r,
                                   const float* __restrict__ leakp,
                                   float* __restrict__ out, int T) {
  __shared__ float Bsh[64], Ssh[64];
  const float leakv = leakp[0];
  const int i = threadIdx.x;                 // 0..63
  const int chunk = (T + 63) / 64;
  const int t0 = i * chunk;
  float B = 0.0f;
  for (int j = 0; j < chunk; ++j) {
    int t = t0 + j;
    if (t < T) B = leakv * B + r[t];
  }
  Bsh[i] = B;
  float A = 1.0f, p = leakv; int e = chunk;
  while (e) { if (e & 1) A *= p; p *= p; e >>= 1; }
  __syncthreads();
  if (i == 0) {
    float dm = 0.0f;
    for (int k = 0; k < 64; ++k) { Ssh[k] = dm; dm = A * dm + Bsh[k]; }
  }
  __syncthreads();
  float dm = Ssh[i];
  for (int j = 0; j < chunk; ++j) {
    int t = t0 + j;
    if (t < T) { dm = leakv * dm + r[t]; out[t] = dm; }
  }
}

// ---------------------------------------------------------------------------
extern "C" void kernel_launch(void* const* d_in, const int* in_sizes, int n_in,
                              void* d_out, int out_size, void* d_ws, size_t ws_size,
                              hipStream_t stream) {
  const float* X  = (const float*)d_in[0];
  const float* st = (const float*)d_in[1];
  const float* W1 = (const float*)d_in[2];
  const float* W2 = (const float*)d_in[3];
  const float* a  = (const float*)d_in[4];
  const float* b  = (const float*)d_in[5];
  const float* c  = (const float*)d_in[6];
  const float* d  = (const float*)d_in[7];
  const float* th = (const float*)d_in[8];
  const float* dt = (const float*)d_in[9];
  const float* lk = (const float*)d_in[10];
  const int N = in_sizes[4];          // a has N elements
  const int T = in_sizes[0] / N;

  float* o_s  = (float*)d_out;               // outputs  [T,N]
  float* o_st = o_s + (long)T * N;           // states   [T,2,N]
  float* o_dm = o_st + 2L * (long)T * N;     // decoded  [T,1]

  int*   cnts = (int*)d_ws;                  // N
  int*   cols = cnts + N;                    // N*CAP
  float* wts  = (float*)(cols + (long)N * CAP); // N*CAP
  float* rbuf = wts + (long)N * CAP;         // T
  float* dump = rbuf + T;                    // toucher sink

  sparsify_kernel<<<N, 256, 0, stream>>>(W1, N, cnts, cols, wts);
  const long n4 = ((long)T * N) / 4;
  touch_kernel<<<1024, 256, 0, stream>>>((const float4*)X, n4, dump);
  const int nblk = (N + 63) / 64;
  izh_pc_kernel<<<nblk, 256, 0, stream>>>(X, st, a, b, c, d, th, dt, W1,
                                          cnts, cols, wts, o_s, o_st, T, N);
  decode_dot_kernel<<<T, 256, 0, stream>>>(o_s, W2, rbuf, N);
  decode_scan_kernel<<<1, 64, 0, stream>>>(rbuf, lk, o_dm, T);
}